// Round 2
// baseline (5319.091 us; speedup 1.0000x reference)
//
#include <hip/hip_runtime.h>

#define SEQ     4096
#define BATCH   2
#define NROWS   8192        // BATCH*SEQ
#define HID     2048
#define INTER_  4096
#define NHEADS  32
#define HDIM    128
#define NSTATE  128
#define CDIM    4352        // INTER + 2*STATE
#define NPROJ_  8480        // INTER + CDIM + HEADS
#define NCH     16          // SEQ / 256
#define CHUNK_  256

typedef __attribute__((ext_vector_type(8))) short bf16x8;
typedef __attribute__((ext_vector_type(4))) short short4v;
typedef __attribute__((ext_vector_type(4))) float f32x4;

__device__ __forceinline__ float bf2f(short s) {
  union { unsigned u; float f; } x;
  x.u = ((unsigned)(unsigned short)s) << 16;
  return x.f;
}
__device__ __forceinline__ short f2bf(float f) {
  union { float f; unsigned u; } x; x.f = f;
  unsigned r = x.u + 0x7FFFu + ((x.u >> 16) & 1u);
  return (short)(r >> 16);
}

// ---------------- f32 -> bf16 conversion, 4 elems/thread ----------------
__global__ void cvt_bf16(const float* __restrict__ in, short* __restrict__ out, int n4) {
  int i = blockIdx.x * 256 + threadIdx.x;
  if (i >= n4) return;
  f32x4 v = *(const f32x4*)(in + (size_t)i * 4);
  short4v o = { f2bf(v.x), f2bf(v.y), f2bf(v.z), f2bf(v.w) };
  *(short4v*)(out + (size_t)i * 4) = o;
}

// ---------------- bf16 MFMA GEMM: C = A(MxK) @ Bw(NxK)^T ----------------
// MODE 0: write f32 to outF (ld = N).  MODE 1: in_proj split epilogue.
template<int MODE>
__global__ __launch_bounds__(256)
void gemm_bf16(const short* __restrict__ A, const short* __restrict__ Bw,
               int M, int N, int K, float* __restrict__ outF,
               short* __restrict__ gate, short* __restrict__ hbc,
               float* __restrict__ dtraw)
{
  __shared__ __align__(16) short Al[128 * 72];
  __shared__ __align__(16) short Bl[128 * 72];
  const int tid = threadIdx.x;
  const int wave = tid >> 6, lane = tid & 63;
  const int l16 = lane & 15, lhi = lane >> 4;
  const int wm = wave >> 1, wn = wave & 1;
  const size_t row0 = (size_t)blockIdx.x * 128;
  const int col0 = blockIdx.y * 128;

  f32x4 acc[4][4];
  #pragma unroll
  for (int m = 0; m < 4; ++m)
    #pragma unroll
    for (int n = 0; n < 4; ++n)
      acc[m][n] = (f32x4){0.f, 0.f, 0.f, 0.f};

  for (int kt = 0; kt < K; kt += 64) {
    #pragma unroll
    for (int i = 0; i < 4; ++i) {
      int f = i * 256 + tid, r = f >> 3, c8 = f & 7;
      *(bf16x8*)(Al + r * 72 + c8 * 8) =
          *(const bf16x8*)(A + (row0 + r) * K + kt + c8 * 8);
    }
    #pragma unroll
    for (int i = 0; i < 4; ++i) {
      int f = i * 256 + tid, r = f >> 3, c8 = f & 7;
      int gn = col0 + r;
      bf16x8 v = {0,0,0,0,0,0,0,0};
      if (gn < N) v = *(const bf16x8*)(Bw + (size_t)gn * K + kt + c8 * 8);
      *(bf16x8*)(Bl + r * 72 + c8 * 8) = v;
    }
    __syncthreads();
    #pragma unroll
    for (int kk = 0; kk < 64; kk += 32) {
      bf16x8 af[4], bfr[4];
      #pragma unroll
      for (int m = 0; m < 4; ++m)
        af[m] = *(const bf16x8*)(Al + (wm * 64 + m * 16 + l16) * 72 + kk + lhi * 8);
      #pragma unroll
      for (int n = 0; n < 4; ++n)
        bfr[n] = *(const bf16x8*)(Bl + (wn * 64 + n * 16 + l16) * 72 + kk + lhi * 8);
      #pragma unroll
      for (int m = 0; m < 4; ++m)
        #pragma unroll
        for (int n = 0; n < 4; ++n)
          acc[m][n] = __builtin_amdgcn_mfma_f32_16x16x32_bf16(af[m], bfr[n], acc[m][n], 0, 0, 0);
    }
    __syncthreads();
  }

  #pragma unroll
  for (int m = 0; m < 4; ++m) {
    #pragma unroll
    for (int n = 0; n < 4; ++n) {
      #pragma unroll
      for (int j = 0; j < 4; ++j) {
        int gr = (int)row0 + wm * 64 + m * 16 + lhi * 4 + j;
        int gc = col0 + wn * 64 + n * 16 + l16;
        float v = acc[m][n][j];
        if (MODE == 0) {
          if (gc < N) outF[(size_t)gr * N + gc] = v;
        } else {
          if (gc < INTER_)            gate[(size_t)gr * INTER_ + gc] = f2bf(v);
          else if (gc < INTER_ + CDIM) hbc[(size_t)gr * CDIM + (gc - INTER_)] = f2bf(v);
          else if (gc < NPROJ_)        dtraw[(size_t)gr * NHEADS + (gc - INTER_ - CDIM)] = v;
        }
      }
    }
  }
}

// ---------------- depthwise causal conv (K=4) + silu + split ----------------
__global__ __launch_bounds__(256)
void conv_silu(const short* __restrict__ hbc, const float* __restrict__ cw,
               const float* __restrict__ cb, short* __restrict__ xs,
               float* __restrict__ Bb, float* __restrict__ Cb)
{
  int c = blockIdx.x * 256 + threadIdx.x;
  if (c >= CDIM) return;
  int row = blockIdx.y;
  int s = row & (SEQ - 1);
  float acc = cb[c];
  #pragma unroll
  for (int k = 0; k < 4; ++k) {
    int sp = s + k - 3;
    if (sp >= 0)
      acc += bf2f(hbc[(size_t)(row + k - 3) * CDIM + c]) * cw[c * 4 + k];
  }
  float v = acc / (1.f + expf(-acc));   // silu
  if (c < INTER_)             xs[(size_t)row * INTER_ + c] = f2bf(v);
  else if (c < INTER_ + NSTATE) Bb[(size_t)row * NSTATE + (c - INTER_)] = v;
  else                          Cb[(size_t)row * NSTATE + (c - INTER_ - NSTATE)] = v;
}

// ---------------- dt = clip(softplus(dt_raw + bias), 0, 100), in-place ----------------
__global__ void dt_proc(float* __restrict__ dtraw, const float* __restrict__ dtb, int n) {
  int i = blockIdx.x * 256 + threadIdx.x;
  if (i >= n) return;
  float x = dtraw[i] + dtb[i & (NHEADS - 1)];
  float sp = (x > 20.f) ? x : log1pf(expf(x));
  dtraw[i] = fminf(fmaxf(sp, 0.f), 100.f);
}

// ---------------- per-chunk state: cs[n][p] = sum_l B[l,n]*xs[l,p]*dt[l]*exp(alast-acum[l]) ----
__global__ __launch_bounds__(256)
void ssm_state(const short* __restrict__ xs, const float* __restrict__ Bb,
               const float* __restrict__ dt2, const float* __restrict__ Alog,
               float* __restrict__ cs, float* __restrict__ dAsum)
{
  int blk = blockIdx.x;                       // (b*16+c)*32+h
  int h = blk & 31, cc = (blk >> 5) & 15, b = blk >> 9;
  int tid = threadIdx.x;
  size_t row0 = (size_t)b * SEQ + cc * CHUNK_;

  __shared__ float acum[256];
  __shared__ float sdt[256];
  __shared__ __align__(16) float sB[32 * 128];
  __shared__ __align__(16) float sX[32 * 128];

  {
    float Ah = -expf(Alog[h]);
    float d = dt2[(row0 + tid) * NHEADS + h];
    sdt[tid] = d;
    acum[tid] = Ah * d;
  }
  for (int off = 1; off < 256; off <<= 1) {
    __syncthreads();
    float v = (tid >= off) ? acum[tid - off] : 0.f;
    __syncthreads();
    acum[tid] += v;
  }
  __syncthreads();
  float alast = acum[255];

  int tn = tid >> 4, l16 = tid & 15;
  float acc[8][8] = {};

  for (int lt = 0; lt < 256; lt += 32) {
    __syncthreads();
    #pragma unroll
    for (int i = 0; i < 4; ++i) {
      int f = i * 256 + tid, r = f >> 5, c4 = f & 31;
      *(f32x4*)(sB + r * 128 + c4 * 4) =
          *(const f32x4*)(Bb + (row0 + lt + r) * NSTATE + c4 * 4);
    }
    #pragma unroll
    for (int i = 0; i < 2; ++i) {
      int f = i * 256 + tid, r = f >> 4, c8 = f & 15;
      int lg = lt + r;
      float sc = sdt[lg] * expf(alast - acum[lg]);
      bf16x8 v = *(const bf16x8*)(xs + (row0 + lg) * INTER_ + h * HDIM + c8 * 8);
      f32x4 lo = { bf2f(v[0])*sc, bf2f(v[1])*sc, bf2f(v[2])*sc, bf2f(v[3])*sc };
      f32x4 hi = { bf2f(v[4])*sc, bf2f(v[5])*sc, bf2f(v[6])*sc, bf2f(v[7])*sc };
      *(f32x4*)(sX + r * 128 + c8 * 8) = lo;
      *(f32x4*)(sX + r * 128 + c8 * 8 + 4) = hi;
    }
    __syncthreads();
    for (int l = 0; l < 32; ++l) {
      f32x4 b0 = *(const f32x4*)(sB + l * 128 + tn * 8);
      f32x4 b1 = *(const f32x4*)(sB + l * 128 + tn * 8 + 4);
      f32x4 x0 = *(const f32x4*)(sX + l * 128 + l16 * 4);
      f32x4 x1 = *(const f32x4*)(sX + l * 128 + 64 + l16 * 4);
      float bn[8] = {b0.x,b0.y,b0.z,b0.w,b1.x,b1.y,b1.z,b1.w};
      float xp[8] = {x0.x,x0.y,x0.z,x0.w,x1.x,x1.y,x1.z,x1.w};
      #pragma unroll
      for (int i = 0; i < 8; ++i)
        #pragma unroll
        for (int j = 0; j < 8; ++j)
          acc[i][j] += bn[i] * xp[j];
    }
  }

  size_t base = (size_t)blk * (NSTATE * HDIM);
  #pragma unroll
  for (int i = 0; i < 8; ++i) {
    int n = tn * 8 + i;
    f32x4 v0 = {acc[i][0], acc[i][1], acc[i][2], acc[i][3]};
    f32x4 v1 = {acc[i][4], acc[i][5], acc[i][6], acc[i][7]};
    *(f32x4*)(cs + base + (size_t)n * HDIM + l16 * 4) = v0;
    *(f32x4*)(cs + base + (size_t)n * HDIM + 64 + l16 * 4) = v1;
  }
  if (tid == 0) dAsum[blk] = alast;
}

// ---------------- inter-chunk sequential scan (IN-PLACE: cs -> prev-state) ----------------
__global__ void ssm_scan(float* __restrict__ cs, const float* __restrict__ dAsum) {
  int idx = blockIdx.x * 256 + threadIdx.x;   // over BATCH*HEADS*16384
  int np = idx & 16383;
  int bh = idx >> 14;
  int h = bh & 31, b = bh >> 5;
  float run = 0.f;
  #pragma unroll
  for (int c = 0; c < NCH; ++c) {
    size_t base = ((size_t)((b * NCH + c) * NHEADS + h)) * 16384 + np;
    float v = cs[base];           // chunk state of chunk c
    cs[base] = run;               // becomes prev-state for chunk c
    run = run * expf(dAsum[(b * NCH + c) * NHEADS + h]) + v;
  }
}

// ---------------- Y = (masked-decay C B^T) @ xdt + exp(acum) * C @ S_prev + D*xs;
//                  then y *= silu(gate); write bf16 IN-PLACE over gate buffer ----
__global__ __launch_bounds__(256)
void ssm_y(const short* __restrict__ xs, const float* __restrict__ Bb,
           const float* __restrict__ Cbuf, const float* __restrict__ dt2,
           const float* __restrict__ Alog, const float* __restrict__ Dv,
           const float* __restrict__ spv, short* __restrict__ gateY)
{
  int blk = blockIdx.y;
  int lt = blockIdx.x;                        // l-tile of 64 (0..3)
  int h = blk & 31, cc = (blk >> 5) & 15, b = blk >> 9;
  int tid = threadIdx.x;
  size_t row0 = (size_t)b * SEQ + cc * CHUNK_;

  __shared__ float acum[256];
  __shared__ float sdt[256];
  __shared__ __align__(16) float sStage[32 * 128];   // 16KB: B^T / xdt / S_prev tiles
  __shared__ __align__(16) float sStage2[64 * 32];   // 8KB : C^T / C*expA tiles
  __shared__ __align__(16) short M_lds[64 * 264];

  { float Ah = -expf(Alog[h]); float d = dt2[(row0 + tid) * NHEADS + h];
    sdt[tid] = d; acum[tid] = Ah * d; }
  for (int off = 1; off < 256; off <<= 1) {
    __syncthreads();
    float v = (tid >= off) ? acum[tid - off] : 0.f;
    __syncthreads();
    acum[tid] += v;
  }
  __syncthreads();

  // ---- phase 1: M[l(64), s(256)] = C_l . B_s  (then decay+mask -> LDS bf16)
  int lg4 = tid >> 4;        // l-group: l = lg4*4 + i
  int l16p = tid & 15;       // s ownership: s = jb*64 + l16p*4 + q
  float mreg[4][16] = {};
  for (int nt = 0; nt < NSTATE; nt += 16) {
    __syncthreads();
    #pragma unroll
    for (int i = 0; i < 4; ++i) {            // B^T stage: [nn(16)][s(256)]
      int f = i * 256 + tid, srow = f >> 2, g = f & 3;
      f32x4 v = *(const f32x4*)(Bb + (row0 + srow) * NSTATE + nt + g * 4);
      sStage[(g * 4 + 0) * 256 + srow] = v.x;
      sStage[(g * 4 + 1) * 256 + srow] = v.y;
      sStage[(g * 4 + 2) * 256 + srow] = v.z;
      sStage[(g * 4 + 3) * 256 + srow] = v.w;
    }
    {                                        // C^T stage: [nn(16)][l(64)]
      int lrow = tid >> 2, g = tid & 3;
      f32x4 v = *(const f32x4*)(Cbuf + (row0 + lt * 64 + lrow) * NSTATE + nt + g * 4);
      sStage2[(g * 4 + 0) * 64 + lrow] = v.x;
      sStage2[(g * 4 + 1) * 64 + lrow] = v.y;
      sStage2[(g * 4 + 2) * 64 + lrow] = v.z;
      sStage2[(g * 4 + 3) * 64 + lrow] = v.w;
    }
    __syncthreads();
    #pragma unroll
    for (int nn = 0; nn < 16; ++nn) {
      f32x4 cl = *(const f32x4*)(sStage2 + nn * 64 + lg4 * 4);
      float clA[4] = {cl.x, cl.y, cl.z, cl.w};
      #pragma unroll
      for (int jb = 0; jb < 4; ++jb) {
        f32x4 bs = *(const f32x4*)(sStage + nn * 256 + jb * 64 + l16p * 4);
        float bsA[4] = {bs.x, bs.y, bs.z, bs.w};
        #pragma unroll
        for (int i = 0; i < 4; ++i)
          #pragma unroll
          for (int q = 0; q < 4; ++q)
            mreg[i][jb * 4 + q] += clA[i] * bsA[q];
      }
    }
  }
  #pragma unroll
  for (int i = 0; i < 4; ++i) {
    int ll = lg4 * 4 + i;
    int lgl = lt * 64 + ll;
    float al = acum[lgl];
    #pragma unroll
    for (int jb = 0; jb < 4; ++jb) {
      short4v mo;
      #pragma unroll
      for (int q = 0; q < 4; ++q) {
        int sg = jb * 64 + l16p * 4 + q;
        float v = (sg <= lgl) ? mreg[i][jb * 4 + q] * expf(al - acum[sg]) : 0.f;
        mo[q] = f2bf(v);
      }
      *(short4v*)(M_lds + ll * 264 + jb * 64 + l16p * 4) = mo;
    }
  }
  __syncthreads();

  // ---- phase 2: Y_diag = M @ xdt
  int tl = tid >> 5;            // l rows tl*8..+8 (local)
  int p0 = (tid & 31) * 4;
  float acc2[8][4] = {};
  int smax = (lt + 1) * 64;     // skip fully-masked s tiles
  for (int st = 0; st < smax; st += 32) {
    __syncthreads();
    #pragma unroll
    for (int i = 0; i < 2; ++i) {
      int f = i * 256 + tid, r = f >> 4, c8 = f & 15;
      float d = sdt[st + r];
      bf16x8 v = *(const bf16x8*)(xs + (row0 + st + r) * INTER_ + h * HDIM + c8 * 8);
      f32x4 lo = { bf2f(v[0])*d, bf2f(v[1])*d, bf2f(v[2])*d, bf2f(v[3])*d };
      f32x4 hi = { bf2f(v[4])*d, bf2f(v[5])*d, bf2f(v[6])*d, bf2f(v[7])*d };
      *(f32x4*)(sStage + r * 128 + c8 * 8) = lo;
      *(f32x4*)(sStage + r * 128 + c8 * 8 + 4) = hi;
    }
    __syncthreads();
    for (int s = 0; s < 32; ++s) {
      int sg = st + s;
      f32x4 x4 = *(const f32x4*)(sStage + s * 128 + p0);
      #pragma unroll
      for (int i = 0; i < 8; ++i) {
        float m = bf2f(M_lds[(tl * 8 + i) * 264 + sg]);
        acc2[i][0] += m * x4.x; acc2[i][1] += m * x4.y;
        acc2[i][2] += m * x4.z; acc2[i][3] += m * x4.w;
      }
    }
  }

  // ---- phase 3: Y_off = (C * exp(acum)) @ S_prev
  for (int nt = 0; nt < NSTATE; nt += 32) {
    __syncthreads();
    #pragma unroll
    for (int i = 0; i < 4; ++i) {
      int f = i * 256 + tid, r = f >> 5, c4 = f & 31;
      *(f32x4*)(sStage + r * 128 + c4 * 4) =
          *(const f32x4*)(spv + (size_t)blk * 16384 + (size_t)(nt + r) * 128 + c4 * 4);
    }
    #pragma unroll
    for (int i = 0; i < 2; ++i) {
      int f = i * 256 + tid, r = f >> 3, g = f & 7;
      float e = expf(acum[lt * 64 + r]);
      f32x4 v = *(const f32x4*)(Cbuf + (row0 + lt * 64 + r) * NSTATE + nt + g * 4);
      v.x *= e; v.y *= e; v.z *= e; v.w *= e;
      *(f32x4*)(sStage2 + r * 32 + g * 4) = v;
    }
    __syncthreads();
    for (int n = 0; n < 32; ++n) {
      f32x4 s4 = *(const f32x4*)(sStage + n * 128 + p0);
      #pragma unroll
      for (int i = 0; i < 8; ++i) {
        float cv = sStage2[(tl * 8 + i) * 32 + n];
        acc2[i][0] += cv * s4.x; acc2[i][1] += cv * s4.y;
        acc2[i][2] += cv * s4.z; acc2[i][3] += cv * s4.w;
      }
    }
  }

  // ---- write: y = (Y + D*xs) * silu(gate), bf16, IN-PLACE over gate buffer
  float Dh = Dv[h];
  #pragma unroll
  for (int i = 0; i < 8; ++i) {
    int ll = tl * 8 + i;
    size_t row = row0 + lt * 64 + ll;
    size_t base = row * INTER_ + h * HDIM + p0;
    short4v xv = *(const short4v*)(xs + base);
    short4v gv = *(const short4v*)(gateY + base);
    short4v ov;
    #pragma unroll
    for (int q = 0; q < 4; ++q) {
      float yv = acc2[i][q] + Dh * bf2f(xv[q]);
      float g = bf2f(gv[q]);
      ov[q] = f2bf(yv * g / (1.f + expf(-g)));
    }
    *(short4v*)(gateY + base) = ov;
  }
}

// ---------------- RMSNorm in-place on bf16 gated y ----------------
__global__ __launch_bounds__(256)
void gate_norm(short* __restrict__ ybf, const float* __restrict__ nw)
{
  int row = blockIdx.x;
  int tid = threadIdx.x;
  size_t base = (size_t)row * INTER_;
  float vals[16];
  float ss = 0.f;
  #pragma unroll
  for (int i = 0; i < 16; ++i) {
    int idx = tid + i * 256;
    float v = bf2f(ybf[base + idx]);
    vals[i] = v;
    ss += v * v;
  }
  #pragma unroll
  for (int off = 32; off > 0; off >>= 1) ss += __shfl_down(ss, off);
  __shared__ float ws4[4];
  if ((tid & 63) == 0) ws4[tid >> 6] = ss;
  __syncthreads();
  float tot = ws4[0] + ws4[1] + ws4[2] + ws4[3];
  float scale = rsqrtf(tot * (1.f / 4096.f) + 1e-5f);
  #pragma unroll
  for (int i = 0; i < 16; ++i) {
    int idx = tid + i * 256;
    ybf[base + idx] = f2bf(vals[i] * scale * nw[idx]);
  }
}

// ---------------- launch ----------------
extern "C" void kernel_launch(void* const* d_in, const int* in_sizes, int n_in,
                              void* d_out, int out_size, void* d_ws, size_t ws_size,
                              hipStream_t stream)
{
  const float* Xf   = (const float*)d_in[0];
  const float* W1f  = (const float*)d_in[1];
  const float* cw   = (const float*)d_in[2];
  const float* cb   = (const float*)d_in[3];
  const float* Alog = (const float*)d_in[4];
  const float* dtb  = (const float*)d_in[5];
  const float* Dv   = (const float*)d_in[6];
  const float* nw   = (const float*)d_in[7];
  const float* W2f  = (const float*)d_in[8];
  float* outp = (float*)d_out;
  char* ws = (char*)d_ws;

  // ---- workspace layout: 232.9 MB total (lifetime-aliased) ----
  // R0 [0, 68.3MB):   Xb(33.5)+W1b(34.7)  --gemm1-->  dead  --> xsb(67.1)
  // R1 [68.3, 85.1):  W2b (16.8)
  // R2 [85.1, 152.2): gate (67.1)  --ssm_y in-place--> gated y bf16 --> norm in-place
  // R3 [152.2,223.5): hbc (71.3)  --> cs (67.1) --> scan in-place --> spv
  // R4 [223.5,224.5): dt (1.0, softplus in-place)
  // R5 [224.5,232.9): Bb(4.2) Cb(4.2) dAs(4KB)
  size_t off = 0;
  short* Xb  = (short*)(ws + off); off += (size_t)NROWS * HID * 2;
  short* W1b = (short*)(ws + off); off += (size_t)NPROJ_ * HID * 2;
  short* xsb = (short*)ws;                         // alias over Xb+W1b (dead after gemm1)
  short* W2b = (short*)(ws + off); off += (size_t)HID * INTER_ * 2;
  short* gateY = (short*)(ws + off); off += (size_t)NROWS * INTER_ * 2;
  short* hbc  = (short*)(ws + off); off += (size_t)NROWS * CDIM * 2;
  float* dtv  = (float*)(ws + off); off += (size_t)NROWS * NHEADS * 4;
  float* Bb   = (float*)(ws + off); off += (size_t)NROWS * NSTATE * 4;
  float* Cb   = (float*)(ws + off); off += (size_t)NROWS * NSTATE * 4;
  float* dAs  = (float*)(ws + off); off += 4096;
  float* cs   = (float*)hbc;                       // alias over hbc (dead after conv)
  // total off = 232,919,040 bytes

  cvt_bf16<<<(NROWS * HID / 4 + 255) / 256, 256, 0, stream>>>(Xf, Xb, NROWS * HID / 4);
  cvt_bf16<<<(NPROJ_ * HID / 4 + 255) / 256, 256, 0, stream>>>(W1f, W1b, NPROJ_ * HID / 4);
  cvt_bf16<<<(HID * INTER_ / 4 + 255) / 256, 256, 0, stream>>>(W2f, W2b, HID * INTER_ / 4);

  gemm_bf16<1><<<dim3(NROWS / 128, (NPROJ_ + 127) / 128), 256, 0, stream>>>(
      Xb, W1b, NROWS, NPROJ_, HID, nullptr, gateY, hbc, dtv);

  dt_proc<<<(NROWS * NHEADS) / 256, 256, 0, stream>>>(dtv, dtb, NROWS * NHEADS);
  conv_silu<<<dim3(17, NROWS), 256, 0, stream>>>(hbc, cw, cb, xsb, Bb, Cb);

  ssm_state<<<BATCH * NCH * NHEADS, 256, 0, stream>>>(xsb, Bb, dtv, Alog, cs, dAs);
  ssm_scan<<<(BATCH * NHEADS * 16384) / 256, 256, 0, stream>>>(cs, dAs);
  ssm_y<<<dim3(4, BATCH * NCH * NHEADS), 256, 0, stream>>>(xsb, Bb, Cb, dtv, Alog, Dv, cs, gateY);

  gate_norm<<<NROWS, 256, 0, stream>>>(gateY, nw);

  gemm_bf16<0><<<dim3(NROWS / 128, HID / 128), 256, 0, stream>>>(
      gateY, W2b, NROWS, HID, INTER_, outp, nullptr, nullptr, nullptr);
}

// Round 3
// 1201.621 us; speedup vs baseline: 4.4266x; 4.4266x over previous
//
#include <hip/hip_runtime.h>

#define SEQ     4096
#define BATCH   2
#define NROWS   8192        // BATCH*SEQ
#define HID     2048
#define INTER_  4096
#define NHEADS  32
#define HDIM    128
#define NSTATE  128
#define CDIM    4352        // INTER + 2*STATE
#define NPROJ_  8480        // INTER + CDIM + HEADS
#define NCH     16          // SEQ / 256
#define CHUNK_  256

typedef __attribute__((ext_vector_type(8))) short bf16x8;
typedef __attribute__((ext_vector_type(4))) short short4v;
typedef __attribute__((ext_vector_type(4))) float f32x4;

__device__ __forceinline__ float bf2f(short s) {
  union { unsigned u; float f; } x;
  x.u = ((unsigned)(unsigned short)s) << 16;
  return x.f;
}
__device__ __forceinline__ short f2bf(float f) {
  union { float f; unsigned u; } x; x.f = f;
  unsigned r = x.u + 0x7FFFu + ((x.u >> 16) & 1u);
  return (short)(r >> 16);
}

// ---------------- f32 -> bf16 conversion, 4 elems/thread ----------------
__global__ void cvt_bf16(const float* __restrict__ in, short* __restrict__ out, int n4) {
  int i = blockIdx.x * 256 + threadIdx.x;
  if (i >= n4) return;
  f32x4 v = *(const f32x4*)(in + (size_t)i * 4);
  short4v o = { f2bf(v.x), f2bf(v.y), f2bf(v.z), f2bf(v.w) };
  *(short4v*)(out + (size_t)i * 4) = o;
}

// ---------------- bf16 MFMA GEMM: C = A(MxK) @ Bw(NxK)^T ----------------
template<int MODE>
__global__ __launch_bounds__(256)
void gemm_bf16(const short* __restrict__ A, const short* __restrict__ Bw,
               int M, int N, int K, float* __restrict__ outF,
               short* __restrict__ gate, short* __restrict__ hbc,
               float* __restrict__ dtraw)
{
  __shared__ __align__(16) short Al[128 * 72];
  __shared__ __align__(16) short Bl[128 * 72];
  const int tid = threadIdx.x;
  const int wave = tid >> 6, lane = tid & 63;
  const int l16 = lane & 15, lhi = lane >> 4;
  const int wm = wave >> 1, wn = wave & 1;
  const size_t row0 = (size_t)blockIdx.x * 128;
  const int col0 = blockIdx.y * 128;

  f32x4 acc[4][4];
  #pragma unroll
  for (int m = 0; m < 4; ++m)
    #pragma unroll
    for (int n = 0; n < 4; ++n)
      acc[m][n] = (f32x4){0.f, 0.f, 0.f, 0.f};

  for (int kt = 0; kt < K; kt += 64) {
    #pragma unroll
    for (int i = 0; i < 4; ++i) {
      int f = i * 256 + tid, r = f >> 3, c8 = f & 7;
      *(bf16x8*)(Al + r * 72 + c8 * 8) =
          *(const bf16x8*)(A + (row0 + r) * K + kt + c8 * 8);
    }
    #pragma unroll
    for (int i = 0; i < 4; ++i) {
      int f = i * 256 + tid, r = f >> 3, c8 = f & 7;
      int gn = col0 + r;
      bf16x8 v = {0,0,0,0,0,0,0,0};
      if (gn < N) v = *(const bf16x8*)(Bw + (size_t)gn * K + kt + c8 * 8);
      *(bf16x8*)(Bl + r * 72 + c8 * 8) = v;
    }
    __syncthreads();
    #pragma unroll
    for (int kk = 0; kk < 64; kk += 32) {
      bf16x8 af[4], bfr[4];
      #pragma unroll
      for (int m = 0; m < 4; ++m)
        af[m] = *(const bf16x8*)(Al + (wm * 64 + m * 16 + l16) * 72 + kk + lhi * 8);
      #pragma unroll
      for (int n = 0; n < 4; ++n)
        bfr[n] = *(const bf16x8*)(Bl + (wn * 64 + n * 16 + l16) * 72 + kk + lhi * 8);
      #pragma unroll
      for (int m = 0; m < 4; ++m)
        #pragma unroll
        for (int n = 0; n < 4; ++n)
          acc[m][n] = __builtin_amdgcn_mfma_f32_16x16x32_bf16(af[m], bfr[n], acc[m][n], 0, 0, 0);
    }
    __syncthreads();
  }

  #pragma unroll
  for (int m = 0; m < 4; ++m) {
    #pragma unroll
    for (int n = 0; n < 4; ++n) {
      #pragma unroll
      for (int j = 0; j < 4; ++j) {
        int gr = (int)row0 + wm * 64 + m * 16 + lhi * 4 + j;
        int gc = col0 + wn * 64 + n * 16 + l16;
        float v = acc[m][n][j];
        if (MODE == 0) {
          if (gc < N) outF[(size_t)gr * N + gc] = v;
        } else {
          if (gc < INTER_)            gate[(size_t)gr * INTER_ + gc] = f2bf(v);
          else if (gc < INTER_ + CDIM) hbc[(size_t)gr * CDIM + (gc - INTER_)] = f2bf(v);
          else if (gc < NPROJ_)        dtraw[(size_t)gr * NHEADS + (gc - INTER_ - CDIM)] = v;
        }
      }
    }
  }
}

// ---------------- depthwise causal conv (K=4) + silu, transposed outputs ----------------
// grid (NROWS/64, 34). ct<32 -> xsT[b][h][p][s]; ct==32 -> Bb natural + BbT[b][n][s]; ct==33 -> Cb natural.
__global__ __launch_bounds__(256)
void conv_t(const short* __restrict__ hbc, const float* __restrict__ cw,
            const float* __restrict__ cb, short* __restrict__ xsT,
            short* __restrict__ Bb, short* __restrict__ Cb, short* __restrict__ BbT)
{
  __shared__ short sOut[64][130];
  int ct = blockIdx.y;
  int cl = threadIdx.x & 127;
  int rh = threadIdx.x >> 7;          // 0,1
  int c = ct * 128 + cl;
  int row0 = blockIdx.x * 64;
  int s0 = row0 & (SEQ - 1);
  float w0 = cw[c * 4 + 0], w1 = cw[c * 4 + 1], w2 = cw[c * 4 + 2], w3 = cw[c * 4 + 3];
  float bias = cb[c];
  int r0 = rh * 32;
  float h0, h1, h2;
  h0 = (s0 + r0 - 3 >= 0) ? bf2f(hbc[(size_t)(row0 + r0 - 3) * CDIM + c]) : 0.f;
  h1 = (s0 + r0 - 2 >= 0) ? bf2f(hbc[(size_t)(row0 + r0 - 2) * CDIM + c]) : 0.f;
  h2 = (s0 + r0 - 1 >= 0) ? bf2f(hbc[(size_t)(row0 + r0 - 1) * CDIM + c]) : 0.f;

  for (int r = r0; r < r0 + 32; ++r) {
    float xin = bf2f(hbc[(size_t)(row0 + r) * CDIM + c]);
    float a = bias + w0 * h0 + w1 * h1 + w2 * h2 + w3 * xin;
    h0 = h1; h1 = h2; h2 = xin;
    float v = a / (1.f + expf(-a));
    short bv = f2bf(v);
    if (ct < 33) sOut[r][cl] = bv;
    if (ct == 32)      Bb[(size_t)(row0 + r) * NSTATE + cl] = bv;
    else if (ct == 33) Cb[(size_t)(row0 + r) * NSTATE + cl] = bv;
  }
  if (ct >= 33) return;               // whole block uniform; no barrier needed after
  __syncthreads();
  // transposed write: thread -> (p, s-half of 32)
  int p = threadIdx.x >> 1, sh = (threadIdx.x & 1) * 32;
  int b = row0 >> 12;
  size_t dst;
  short* outp;
  if (ct < 32) { outp = xsT; dst = ((size_t)(b * 32 + ct) * 128 + p) * SEQ + s0 + sh; }
  else         { outp = BbT; dst = ((size_t)b * 128 + p) * SEQ + s0 + sh; }
  #pragma unroll
  for (int g = 0; g < 8; ++g) {
    short4v o;
    o[0] = sOut[sh + g * 4 + 0][p];
    o[1] = sOut[sh + g * 4 + 1][p];
    o[2] = sOut[sh + g * 4 + 2][p];
    o[3] = sOut[sh + g * 4 + 3][p];
    *(short4v*)(outp + dst + g * 4) = o;
  }
}

// ---------------- dt = clip(softplus(dt_raw + bias), 0, 100) -> transposed dtT[h][row] ----
__global__ void dt_proc(const float* __restrict__ dtraw, const float* __restrict__ dtb,
                        float* __restrict__ dtT, int n) {
  int i = blockIdx.x * 256 + threadIdx.x;
  if (i >= n) return;
  float x = dtraw[i] + dtb[i & (NHEADS - 1)];
  float sp = (x > 20.f) ? x : log1pf(expf(x));
  float d = fminf(fmaxf(sp, 0.f), 100.f);
  int row = i >> 5, h = i & 31;
  dtT[(size_t)h * NROWS + row] = d;
}

// ---------------- chunk state (MFMA): S^T[p][n] = sum_l xdt_decay[l][p] * B[l][n] ----
__global__ __launch_bounds__(256)
void ssm_state(const short* __restrict__ xsT, const short* __restrict__ BbT,
               const float* __restrict__ dtT, const float* __restrict__ Alog,
               float* __restrict__ cs, float* __restrict__ dAsum)
{
  int blk = blockIdx.x;                       // (b*16+cc)*32+h
  int h = blk & 31, cc = (blk >> 5) & 15, b = blk >> 9;
  int tid = threadIdx.x, lane = tid & 63, wave = tid >> 6;
  int l16 = lane & 15, lhi = lane >> 4;
  int s0 = cc * CHUNK_;

  __shared__ float acum[256];
  __shared__ float sdt[256];
  { float Ah = -expf(Alog[h]);
    float d = dtT[(size_t)h * NROWS + (size_t)b * SEQ + s0 + tid];
    sdt[tid] = d; acum[tid] = Ah * d; }
  for (int off = 1; off < 256; off <<= 1) {
    __syncthreads();
    float v = (tid >= off) ? acum[tid - off] : 0.f;
    __syncthreads();
    acum[tid] += v;
  }
  __syncthreads();
  float alast = acum[255];

  const short* xbase = xsT + ((size_t)(b * 32 + h) * 128) * SEQ + s0;
  const short* bbase = BbT + ((size_t)b * 128) * SEQ + s0;

  f32x4 acc[2][8];
  #pragma unroll
  for (int m = 0; m < 2; ++m)
    #pragma unroll
    for (int n = 0; n < 8; ++n) acc[m][n] = (f32x4){0.f, 0.f, 0.f, 0.f};

  for (int lt0 = 0; lt0 < 256; lt0 += 32) {
    float fe[8];
    #pragma unroll
    for (int e = 0; e < 8; ++e) {
      int kl = lt0 + lhi * 8 + e;
      fe[e] = sdt[kl] * __expf(alast - acum[kl]);
    }
    bf16x8 af[2];
    #pragma unroll
    for (int m = 0; m < 2; ++m) {
      bf16x8 raw = *(const bf16x8*)(xbase + (size_t)(wave * 32 + m * 16 + l16) * SEQ + lt0 + lhi * 8);
      bf16x8 sc;
      #pragma unroll
      for (int e = 0; e < 8; ++e) sc[e] = f2bf(bf2f(raw[e]) * fe[e]);
      af[m] = sc;
    }
    #pragma unroll
    for (int n = 0; n < 8; ++n) {
      bf16x8 bfv = *(const bf16x8*)(bbase + (size_t)(n * 16 + l16) * SEQ + lt0 + lhi * 8);
      acc[0][n] = __builtin_amdgcn_mfma_f32_16x16x32_bf16(af[0], bfv, acc[0][n], 0, 0, 0);
      acc[1][n] = __builtin_amdgcn_mfma_f32_16x16x32_bf16(af[1], bfv, acc[1][n], 0, 0, 0);
    }
  }
  size_t base = (size_t)blk * 16384;
  #pragma unroll
  for (int m = 0; m < 2; ++m)
    #pragma unroll
    for (int n = 0; n < 8; ++n)
      #pragma unroll
      for (int j = 0; j < 4; ++j) {
        int p = wave * 32 + m * 16 + lhi * 4 + j;
        int ng = n * 16 + l16;
        cs[base + (size_t)p * NSTATE + ng] = acc[m][n][j];
      }
  if (tid == 0) dAsum[blk] = alast;
}

// ---------------- inter-chunk sequential scan (IN-PLACE: chunk-state -> prev-state) ----
__global__ void ssm_scan(float* __restrict__ cs, const float* __restrict__ dAsum) {
  int idx = blockIdx.x * 256 + threadIdx.x;   // over BATCH*HEADS*16384
  int np = idx & 16383;
  int bh = idx >> 14;
  int h = bh & 31, b = bh >> 5;
  float run = 0.f;
  #pragma unroll
  for (int c = 0; c < NCH; ++c) {
    size_t base = ((size_t)((b * NCH + c) * NHEADS + h)) * 16384 + np;
    float v = cs[base];
    cs[base] = run;
    run = run * __expf(dAsum[(b * NCH + c) * NHEADS + h]) + v;
  }
}

// ---------------- Y (MFMA): Y = M' @ xdt + exp(acum)*(C @ S_prev^T), gate in-place ----
__global__ __launch_bounds__(256)
void ssm_y(const short* __restrict__ xsT, const short* __restrict__ Bb,
           const short* __restrict__ Cb, const float* __restrict__ dtT,
           const float* __restrict__ Alog, const float* __restrict__ Dv,
           const float* __restrict__ cs, short* __restrict__ gateY)
{
  int blk = blockIdx.y, lt = blockIdx.x;
  int h = blk & 31, cc = (blk >> 5) & 15, b = blk >> 9;
  int tid = threadIdx.x, lane = tid & 63, wave = tid >> 6;
  int l16 = lane & 15, lhi = lane >> 4;
  int s0 = cc * CHUNK_;
  size_t row0 = (size_t)b * SEQ + s0;

  __shared__ float acum[256];
  __shared__ float sdt[256];
  __shared__ __align__(16) short M_lds[64 * 264];

  { float Ah = -expf(Alog[h]);
    float d = dtT[(size_t)h * NROWS + row0 + tid];
    sdt[tid] = d; acum[tid] = Ah * d; }
  for (int off = 1; off < 256; off <<= 1) {
    __syncthreads();
    float v = (tid >= off) ? acum[tid - off] : 0.f;
    __syncthreads();
    acum[tid] += v;
  }
  __syncthreads();

  float Dh = Dv[h];

  // ---- phase 1: G = C_l · B^T (global frags), decay+mask(+D/dt diag) -> M_lds bf16
  {
    f32x4 acc1[4][4];
    #pragma unroll
    for (int m = 0; m < 4; ++m)
      #pragma unroll
      for (int n = 0; n < 4; ++n) acc1[m][n] = (f32x4){0.f, 0.f, 0.f, 0.f};
    for (int kk = 0; kk < NSTATE; kk += 32) {
      bf16x8 af[4], bv[4];
      #pragma unroll
      for (int m = 0; m < 4; ++m)
        af[m] = *(const bf16x8*)(Cb + (row0 + lt * 64 + m * 16 + l16) * NSTATE + kk + lhi * 8);
      #pragma unroll
      for (int n = 0; n < 4; ++n)
        bv[n] = *(const bf16x8*)(Bb + (row0 + wave * 64 + n * 16 + l16) * NSTATE + kk + lhi * 8);
      #pragma unroll
      for (int m = 0; m < 4; ++m)
        #pragma unroll
        for (int n = 0; n < 4; ++n)
          acc1[m][n] = __builtin_amdgcn_mfma_f32_16x16x32_bf16(af[m], bv[n], acc1[m][n], 0, 0, 0);
    }
    float as_[4]; int sg_[4];
    #pragma unroll
    for (int n = 0; n < 4; ++n) { sg_[n] = wave * 64 + n * 16 + l16; as_[n] = acum[sg_[n]]; }
    #pragma unroll
    for (int m = 0; m < 4; ++m) {
      #pragma unroll
      for (int j = 0; j < 4; ++j) {
        int ll = m * 16 + lhi * 4 + j;
        int lg = lt * 64 + ll;
        float al = acum[lg];
        float dinv = Dh / fmaxf(sdt[lg], 1e-20f);
        #pragma unroll
        for (int n = 0; n < 4; ++n) {
          float v = 0.f;
          if (sg_[n] <= lg) {
            v = acc1[m][n][j] * __expf(al - as_[n]);
            if (sg_[n] == lg) v += dinv;
          }
          M_lds[ll * 264 + wave * 64 + n * 16 + l16] = f2bf(v);
        }
      }
    }
  }
  __syncthreads();

  const short* xbase = xsT + ((size_t)(b * 32 + h) * 128) * SEQ + s0;

  // ---- phase 2: Y_diag = M' @ xdt  (xdt^T frags direct from xsT global)
  f32x4 accY[4][2];
  #pragma unroll
  for (int m = 0; m < 4; ++m) { accY[m][0] = (f32x4){0,0,0,0}; accY[m][1] = (f32x4){0,0,0,0}; }
  int smax = (lt + 1) * 64;
  for (int st = 0; st < smax; st += 32) {
    float fe[8];
    #pragma unroll
    for (int e = 0; e < 8; ++e) fe[e] = sdt[st + lhi * 8 + e];
    bf16x8 bv2[2];
    #pragma unroll
    for (int n = 0; n < 2; ++n) {
      bf16x8 raw = *(const bf16x8*)(xbase + (size_t)(wave * 32 + n * 16 + l16) * SEQ + st + lhi * 8);
      bf16x8 sc;
      #pragma unroll
      for (int e = 0; e < 8; ++e) sc[e] = f2bf(bf2f(raw[e]) * fe[e]);
      bv2[n] = sc;
    }
    #pragma unroll
    for (int m = 0; m < 4; ++m) {
      bf16x8 a = *(const bf16x8*)(M_lds + (m * 16 + l16) * 264 + st + lhi * 8);
      accY[m][0] = __builtin_amdgcn_mfma_f32_16x16x32_bf16(a, bv2[0], accY[m][0], 0, 0, 0);
      accY[m][1] = __builtin_amdgcn_mfma_f32_16x16x32_bf16(a, bv2[1], accY[m][1], 0, 0, 0);
    }
  }

  // ---- phase 3: Y_off = C @ S_prev^T (S^T frags direct from cs f32 global)
  f32x4 accO[4][2];
  #pragma unroll
  for (int m = 0; m < 4; ++m) { accO[m][0] = (f32x4){0,0,0,0}; accO[m][1] = (f32x4){0,0,0,0}; }
  size_t pbase = (size_t)blk * 16384;
  for (int nt = 0; nt < NSTATE; nt += 32) {
    bf16x8 bv2[2];
    #pragma unroll
    for (int n = 0; n < 2; ++n) {
      int p = wave * 32 + n * 16 + l16;
      const float* src = cs + pbase + (size_t)p * NSTATE + nt + lhi * 8;
      f32x4 v0 = *(const f32x4*)src;
      f32x4 v1 = *(const f32x4*)(src + 4);
      bf16x8 sc;
      sc[0] = f2bf(v0.x); sc[1] = f2bf(v0.y); sc[2] = f2bf(v0.z); sc[3] = f2bf(v0.w);
      sc[4] = f2bf(v1.x); sc[5] = f2bf(v1.y); sc[6] = f2bf(v1.z); sc[7] = f2bf(v1.w);
      bv2[n] = sc;
    }
    #pragma unroll
    for (int m = 0; m < 4; ++m) {
      bf16x8 a = *(const bf16x8*)(Cb + (row0 + lt * 64 + m * 16 + l16) * NSTATE + nt + lhi * 8);
      accO[m][0] = __builtin_amdgcn_mfma_f32_16x16x32_bf16(a, bv2[0], accO[m][0], 0, 0, 0);
      accO[m][1] = __builtin_amdgcn_mfma_f32_16x16x32_bf16(a, bv2[1], accO[m][1], 0, 0, 0);
    }
  }

  // ---- epilogue: Y = accY + exp(acum[l])*accO; gate in place
  #pragma unroll
  for (int m = 0; m < 4; ++m) {
    #pragma unroll
    for (int j = 0; j < 4; ++j) {
      int ll = m * 16 + lhi * 4 + j;
      float e = __expf(acum[lt * 64 + ll]);
      size_t row = row0 + lt * 64 + ll;
      #pragma unroll
      for (int n = 0; n < 2; ++n) {
        int p = wave * 32 + n * 16 + l16;
        size_t adr = row * INTER_ + h * HDIM + p;
        float yv = accY[m][n][j] + e * accO[m][n][j];
        float g = bf2f(gateY[adr]);
        gateY[adr] = f2bf(yv * g / (1.f + expf(-g)));
      }
    }
  }
}

// ---------------- RMSNorm in-place on bf16 gated y ----------------
__global__ __launch_bounds__(256)
void gate_norm(short* __restrict__ ybf, const float* __restrict__ nw)
{
  int row = blockIdx.x;
  int tid = threadIdx.x;
  size_t base = (size_t)row * INTER_;
  float vals[16];
  float ss = 0.f;
  #pragma unroll
  for (int i = 0; i < 16; ++i) {
    int idx = tid + i * 256;
    float v = bf2f(ybf[base + idx]);
    vals[i] = v;
    ss += v * v;
  }
  #pragma unroll
  for (int off = 32; off > 0; off >>= 1) ss += __shfl_down(ss, off);
  __shared__ float ws4[4];
  if ((tid & 63) == 0) ws4[tid >> 6] = ss;
  __syncthreads();
  float tot = ws4[0] + ws4[1] + ws4[2] + ws4[3];
  float scale = rsqrtf(tot * (1.f / 4096.f) + 1e-5f);
  #pragma unroll
  for (int i = 0; i < 16; ++i) {
    int idx = tid + i * 256;
    ybf[base + idx] = f2bf(vals[i] * scale * nw[idx]);
  }
}

// ---------------- launch ----------------
extern "C" void kernel_launch(void* const* d_in, const int* in_sizes, int n_in,
                              void* d_out, int out_size, void* d_ws, size_t ws_size,
                              hipStream_t stream)
{
  const float* Xf   = (const float*)d_in[0];
  const float* W1f  = (const float*)d_in[1];
  const float* cw   = (const float*)d_in[2];
  const float* cb   = (const float*)d_in[3];
  const float* Alog = (const float*)d_in[4];
  const float* dtb  = (const float*)d_in[5];
  const float* Dv   = (const float*)d_in[6];
  const float* nw   = (const float*)d_in[7];
  const float* W2f  = (const float*)d_in[8];
  float* outp = (float*)d_out;
  char* ws = (char*)d_ws;

  // ---- workspace layout: ~231.9 MB (lifetime-aliased) ----
  size_t off = 0;
  short* Xb  = (short*)(ws + off); off += (size_t)NROWS * HID * 2;      // 33.55 MB
  short* W1b = (short*)(ws + off); off += (size_t)NPROJ_ * HID * 2;     // 34.73 MB
  short* xsT = (short*)ws;   // alias over Xb+W1b (dead after gemm1): 67.1 <= 68.3 MB
  short* W2b = (short*)(ws + off); off += (size_t)HID * INTER_ * 2;     // 16.78 MB
  short* gateY = (short*)(ws + off); off += (size_t)NROWS * INTER_ * 2; // 67.11 MB
  short* hbc  = (short*)(ws + off); off += (size_t)NROWS * CDIM * 2;    // 71.30 MB
  float* dtv  = (float*)(ws + off); off += (size_t)NROWS * NHEADS * 4;  // 1.05 MB
  float* dtT  = (float*)(ws + off); off += (size_t)NROWS * NHEADS * 4;  // 1.05 MB
  short* Bb   = (short*)(ws + off); off += (size_t)NROWS * NSTATE * 2;  // 2.10 MB
  short* Cb   = (short*)(ws + off); off += (size_t)NROWS * NSTATE * 2;  // 2.10 MB
  short* BbT  = (short*)(ws + off); off += (size_t)NROWS * NSTATE * 2;  // 2.10 MB
  float* dAs  = (float*)(ws + off); off += 4096;
  float* cs   = (float*)hbc;  // alias over hbc (dead after conv): 67.1 <= 71.3 MB

  cvt_bf16<<<(NROWS * HID / 4 + 255) / 256, 256, 0, stream>>>(Xf, Xb, NROWS * HID / 4);
  cvt_bf16<<<(NPROJ_ * HID / 4 + 255) / 256, 256, 0, stream>>>(W1f, W1b, NPROJ_ * HID / 4);
  cvt_bf16<<<(HID * INTER_ / 4 + 255) / 256, 256, 0, stream>>>(W2f, W2b, HID * INTER_ / 4);

  gemm_bf16<1><<<dim3(NROWS / 128, (NPROJ_ + 127) / 128), 256, 0, stream>>>(
      Xb, W1b, NROWS, NPROJ_, HID, nullptr, gateY, hbc, dtv);

  dt_proc<<<(NROWS * NHEADS) / 256, 256, 0, stream>>>(dtv, dtb, dtT, NROWS * NHEADS);
  conv_t<<<dim3(NROWS / 64, 34), 256, 0, stream>>>(hbc, cw, cb, xsT, Bb, Cb, BbT);

  ssm_state<<<BATCH * NCH * NHEADS, 256, 0, stream>>>(xsT, BbT, dtT, Alog, cs, dAs);
  ssm_scan<<<(BATCH * NHEADS * 16384) / 256, 256, 0, stream>>>(cs, dAs);
  ssm_y<<<dim3(4, BATCH * NCH * NHEADS), 256, 0, stream>>>(xsT, Bb, Cb, dtT, Alog, Dv, cs, gateY);

  gate_norm<<<NROWS, 256, 0, stream>>>(gateY, nw);

  gemm_bf16<0><<<dim3(NROWS / 128, HID / 128), 256, 0, stream>>>(
      gateY, W2b, NROWS, HID, INTER_, outp, nullptr, nullptr, nullptr);
}

// Round 4
// 995.207 us; speedup vs baseline: 5.3447x; 1.2074x over previous
//
#include <hip/hip_runtime.h>

#define SEQ     4096
#define BATCH   2
#define NROWS   8192        // BATCH*SEQ
#define HID     2048
#define INTER_  4096
#define NHEADS  32
#define HDIM    128
#define NSTATE  128
#define CDIM    4352        // INTER + 2*STATE
#define NPROJ_  8480        // INTER + CDIM + HEADS
#define NPAD    8576        // NPROJ_ padded to 128 (zero-filled W1 rows)
#define NCH     16          // SEQ / 256
#define CHUNK_  256

typedef __attribute__((ext_vector_type(8))) short bf16x8;
typedef __attribute__((ext_vector_type(4))) short short4v;
typedef __attribute__((ext_vector_type(4))) float f32x4;

__device__ __forceinline__ float bf2f(short s) {
  union { unsigned u; float f; } x;
  x.u = ((unsigned)(unsigned short)s) << 16;
  return x.f;
}
__device__ __forceinline__ short f2bf(float f) {
  union { float f; unsigned u; } x; x.f = f;
  unsigned r = x.u + 0x7FFFu + ((x.u >> 16) & 1u);
  return (short)(r >> 16);
}

// ---------------- f32 -> bf16 conversion, 4 elems/thread; zero-pad past nsrc4 ----------------
__global__ void cvt_bf16(const float* __restrict__ in, short* __restrict__ out,
                         int n4, int nsrc4) {
  int i = blockIdx.x * 256 + threadIdx.x;
  if (i >= n4) return;
  short4v o = {0, 0, 0, 0};
  if (i < nsrc4) {
    f32x4 v = *(const f32x4*)(in + (size_t)i * 4);
    o = (short4v){ f2bf(v.x), f2bf(v.y), f2bf(v.z), f2bf(v.w) };
  }
  *(short4v*)(out + (size_t)i * 4) = o;
}

// ---------------- global -> LDS staging: 128x64 bf16 tile, swizzled source ----------------
// LDS linear [128][64]; source column pre-XOR'd so reads XOR the same bits (rule: both sides).
__device__ __forceinline__ void stage_tile(const short* gbase, int ldK, short* lds,
                                           int wave, int lane) {
  #pragma unroll
  for (int i = 0; i < 4; ++i) {
    int c = wave * 4 + i;                       // 1KB chunk 0..15 (8 rows each)
    int r = c * 8 + (lane >> 3);                // local row 0..127
    int colb = ((lane & 7) * 16) ^ (((r >> 2) & 3) << 5);
    const short* g = gbase + (size_t)r * ldK + (colb >> 1);
    short* l = lds + c * 512;                   // wave-uniform base; HW adds lane*16
    __builtin_amdgcn_global_load_lds(
        (const __attribute__((address_space(1))) unsigned int*)g,
        (__attribute__((address_space(3))) unsigned int*)l, 16, 0, 0);
  }
}
__device__ __forceinline__ bf16x8 lds_frag(const short* lds, int r, int colElem) {
  int colb = (colElem * 2) ^ (((r >> 2) & 3) << 5);
  return *(const bf16x8*)((const char*)lds + r * 128 + colb);
}

// ---------------- bf16 MFMA GEMM: C = A(MxK) @ Bw(NpadxK)^T, global_load_lds staging ----
template<int MODE>
__global__ __launch_bounds__(256)
void gemm_bf16(const short* __restrict__ A, const short* __restrict__ Bw,
               int M, int N, int K, float* __restrict__ outF,
               short* __restrict__ gate, short* __restrict__ hbc,
               float* __restrict__ dtraw)
{
  __shared__ __align__(16) short Al[128 * 64];
  __shared__ __align__(16) short Bl[128 * 64];
  const int tid = threadIdx.x;
  const int wave = tid >> 6, lane = tid & 63;
  const int l16 = lane & 15, lhi = lane >> 4;
  const int wm = wave >> 1, wn = wave & 1;
  const size_t row0 = (size_t)blockIdx.x * 128;
  const int col0 = blockIdx.y * 128;

  f32x4 acc[4][4];
  #pragma unroll
  for (int m = 0; m < 4; ++m)
    #pragma unroll
    for (int n = 0; n < 4; ++n)
      acc[m][n] = (f32x4){0.f, 0.f, 0.f, 0.f};

  const short* Abase = A + row0 * K;
  const short* Bbase = Bw + (size_t)col0 * K;

  for (int kt = 0; kt < K; kt += 64) {
    stage_tile(Abase + kt, K, Al, wave, lane);
    stage_tile(Bbase + kt, K, Bl, wave, lane);
    __syncthreads();
    #pragma unroll
    for (int kk = 0; kk < 64; kk += 32) {
      bf16x8 af[4], bfr[4];
      #pragma unroll
      for (int m = 0; m < 4; ++m)
        af[m] = lds_frag(Al, wm * 64 + m * 16 + l16, kk + lhi * 8);
      #pragma unroll
      for (int n = 0; n < 4; ++n)
        bfr[n] = lds_frag(Bl, wn * 64 + n * 16 + l16, kk + lhi * 8);
      #pragma unroll
      for (int m = 0; m < 4; ++m)
        #pragma unroll
        for (int n = 0; n < 4; ++n)
          acc[m][n] = __builtin_amdgcn_mfma_f32_16x16x32_bf16(af[m], bfr[n], acc[m][n], 0, 0, 0);
    }
    __syncthreads();
  }

  #pragma unroll
  for (int m = 0; m < 4; ++m) {
    #pragma unroll
    for (int n = 0; n < 4; ++n) {
      #pragma unroll
      for (int j = 0; j < 4; ++j) {
        int gr = (int)row0 + wm * 64 + m * 16 + lhi * 4 + j;
        int gc = col0 + wn * 64 + n * 16 + l16;
        float v = acc[m][n][j];
        if (MODE == 0) {
          outF[(size_t)gr * N + gc] = v;
        } else {
          if (gc < INTER_)             gate[(size_t)gr * INTER_ + gc] = f2bf(v);
          else if (gc < INTER_ + CDIM) hbc[(size_t)gr * CDIM + (gc - INTER_)] = f2bf(v);
          else if (gc < NPROJ_)        dtraw[(size_t)gr * NHEADS + (gc - INTER_ - CDIM)] = v;
        }
      }
    }
  }
}

// ---------------- depthwise causal conv (K=4) + silu, transposed outputs ----------------
__global__ __launch_bounds__(256)
void conv_t(const short* __restrict__ hbc, const float* __restrict__ cw,
            const float* __restrict__ cb, short* __restrict__ xsT,
            short* __restrict__ Bb, short* __restrict__ Cb, short* __restrict__ BbT)
{
  __shared__ short sOut[64][130];
  int ct = blockIdx.y;
  int cl = threadIdx.x & 127;
  int rh = threadIdx.x >> 7;          // 0,1
  int c = ct * 128 + cl;
  int row0 = blockIdx.x * 64;
  int s0 = row0 & (SEQ - 1);
  float w0 = cw[c * 4 + 0], w1 = cw[c * 4 + 1], w2 = cw[c * 4 + 2], w3 = cw[c * 4 + 3];
  float bias = cb[c];
  int r0 = rh * 32;
  float h0, h1, h2;
  h0 = (s0 + r0 - 3 >= 0) ? bf2f(hbc[(size_t)(row0 + r0 - 3) * CDIM + c]) : 0.f;
  h1 = (s0 + r0 - 2 >= 0) ? bf2f(hbc[(size_t)(row0 + r0 - 2) * CDIM + c]) : 0.f;
  h2 = (s0 + r0 - 1 >= 0) ? bf2f(hbc[(size_t)(row0 + r0 - 1) * CDIM + c]) : 0.f;

  for (int r = r0; r < r0 + 32; ++r) {
    float xin = bf2f(hbc[(size_t)(row0 + r) * CDIM + c]);
    float a = bias + w0 * h0 + w1 * h1 + w2 * h2 + w3 * xin;
    h0 = h1; h1 = h2; h2 = xin;
    float v = a / (1.f + expf(-a));
    short bv = f2bf(v);
    if (ct < 33) sOut[r][cl] = bv;
    if (ct == 32)      Bb[(size_t)(row0 + r) * NSTATE + cl] = bv;
    else if (ct == 33) Cb[(size_t)(row0 + r) * NSTATE + cl] = bv;
  }
  if (ct >= 33) return;
  __syncthreads();
  int p = threadIdx.x >> 1, sh = (threadIdx.x & 1) * 32;
  int b = row0 >> 12;
  size_t dst;
  short* outp;
  if (ct < 32) { outp = xsT; dst = ((size_t)(b * 32 + ct) * 128 + p) * SEQ + s0 + sh; }
  else         { outp = BbT; dst = ((size_t)b * 128 + p) * SEQ + s0 + sh; }
  #pragma unroll
  for (int g = 0; g < 8; ++g) {
    short4v o;
    o[0] = sOut[sh + g * 4 + 0][p];
    o[1] = sOut[sh + g * 4 + 1][p];
    o[2] = sOut[sh + g * 4 + 2][p];
    o[3] = sOut[sh + g * 4 + 3][p];
    *(short4v*)(outp + dst + g * 4) = o;
  }
}

// ---------------- dt = clip(softplus(dt_raw + bias), 0, 100) -> transposed dtT[h][row] ----
__global__ void dt_proc(const float* __restrict__ dtraw, const float* __restrict__ dtb,
                        float* __restrict__ dtT, int n) {
  int i = blockIdx.x * 256 + threadIdx.x;
  if (i >= n) return;
  float x = dtraw[i] + dtb[i & (NHEADS - 1)];
  float sp = (x > 20.f) ? x : log1pf(expf(x));
  float d = fminf(fmaxf(sp, 0.f), 100.f);
  int row = i >> 5, h = i & 31;
  dtT[(size_t)h * NROWS + row] = d;
}

// ---------------- chunk state (MFMA): S^T[p][n] = sum_l xdt_decay[l][p] * B[l][n] ----
__global__ __launch_bounds__(256)
void ssm_state(const short* __restrict__ xsT, const short* __restrict__ BbT,
               const float* __restrict__ dtT, const float* __restrict__ Alog,
               float* __restrict__ cs, float* __restrict__ dAsum)
{
  int blk = blockIdx.x;                       // (b*16+cc)*32+h
  int h = blk & 31, cc = (blk >> 5) & 15, b = blk >> 9;
  int tid = threadIdx.x, lane = tid & 63, wave = tid >> 6;
  int l16 = lane & 15, lhi = lane >> 4;
  int s0 = cc * CHUNK_;

  __shared__ float acum[256];
  __shared__ float sdt[256];
  { float Ah = -expf(Alog[h]);
    float d = dtT[(size_t)h * NROWS + (size_t)b * SEQ + s0 + tid];
    sdt[tid] = d; acum[tid] = Ah * d; }
  for (int off = 1; off < 256; off <<= 1) {
    __syncthreads();
    float v = (tid >= off) ? acum[tid - off] : 0.f;
    __syncthreads();
    acum[tid] += v;
  }
  __syncthreads();
  float alast = acum[255];

  const short* xbase = xsT + ((size_t)(b * 32 + h) * 128) * SEQ + s0;
  const short* bbase = BbT + ((size_t)b * 128) * SEQ + s0;

  f32x4 acc[2][8];
  #pragma unroll
  for (int m = 0; m < 2; ++m)
    #pragma unroll
    for (int n = 0; n < 8; ++n) acc[m][n] = (f32x4){0.f, 0.f, 0.f, 0.f};

  for (int lt0 = 0; lt0 < 256; lt0 += 32) {
    float fe[8];
    #pragma unroll
    for (int e = 0; e < 8; ++e) {
      int kl = lt0 + lhi * 8 + e;
      fe[e] = sdt[kl] * __expf(alast - acum[kl]);
    }
    bf16x8 af[2];
    #pragma unroll
    for (int m = 0; m < 2; ++m) {
      bf16x8 raw = *(const bf16x8*)(xbase + (size_t)(wave * 32 + m * 16 + l16) * SEQ + lt0 + lhi * 8);
      bf16x8 sc;
      #pragma unroll
      for (int e = 0; e < 8; ++e) sc[e] = f2bf(bf2f(raw[e]) * fe[e]);
      af[m] = sc;
    }
    #pragma unroll
    for (int n = 0; n < 8; ++n) {
      bf16x8 bfv = *(const bf16x8*)(bbase + (size_t)(n * 16 + l16) * SEQ + lt0 + lhi * 8);
      acc[0][n] = __builtin_amdgcn_mfma_f32_16x16x32_bf16(af[0], bfv, acc[0][n], 0, 0, 0);
      acc[1][n] = __builtin_amdgcn_mfma_f32_16x16x32_bf16(af[1], bfv, acc[1][n], 0, 0, 0);
    }
  }
  size_t base = (size_t)blk * 16384;
  #pragma unroll
  for (int m = 0; m < 2; ++m)
    #pragma unroll
    for (int n = 0; n < 8; ++n)
      #pragma unroll
      for (int j = 0; j < 4; ++j) {
        int p = wave * 32 + m * 16 + lhi * 4 + j;
        int ng = n * 16 + l16;
        cs[base + (size_t)p * NSTATE + ng] = acc[m][n][j];
      }
  if (tid == 0) dAsum[blk] = alast;
}

// ---------------- inter-chunk sequential scan (IN-PLACE: chunk-state -> prev-state) ----
__global__ void ssm_scan(float* __restrict__ cs, const float* __restrict__ dAsum) {
  int idx = blockIdx.x * 256 + threadIdx.x;   // over BATCH*HEADS*16384
  int np = idx & 16383;
  int bh = idx >> 14;
  int h = bh & 31, b = bh >> 5;
  float run = 0.f;
  #pragma unroll
  for (int c = 0; c < NCH; ++c) {
    size_t base = ((size_t)((b * NCH + c) * NHEADS + h)) * 16384 + np;
    float v = cs[base];
    cs[base] = run;
    run = run * __expf(dAsum[(b * NCH + c) * NHEADS + h]) + v;
  }
}

// ---------------- Y (MFMA): Y = M' @ xdt + exp(acum)*(C @ S_prev^T), gate in-place ----
__global__ __launch_bounds__(256)
void ssm_y(const short* __restrict__ xsT, const short* __restrict__ Bb,
           const short* __restrict__ Cb, const float* __restrict__ dtT,
           const float* __restrict__ Alog, const float* __restrict__ Dv,
           const float* __restrict__ cs, short* __restrict__ gateY)
{
  int blk = blockIdx.y, lt = blockIdx.x;
  int h = blk & 31, cc = (blk >> 5) & 15, b = blk >> 9;
  int tid = threadIdx.x, lane = tid & 63, wave = tid >> 6;
  int l16 = lane & 15, lhi = lane >> 4;
  int s0 = cc * CHUNK_;
  size_t row0 = (size_t)b * SEQ + s0;

  __shared__ float acum[256];
  __shared__ float sdt[256];
  __shared__ __align__(16) short M_lds[64 * 264];

  { float Ah = -expf(Alog[h]);
    float d = dtT[(size_t)h * NROWS + row0 + tid];
    sdt[tid] = d; acum[tid] = Ah * d; }
  for (int off = 1; off < 256; off <<= 1) {
    __syncthreads();
    float v = (tid >= off) ? acum[tid - off] : 0.f;
    __syncthreads();
    acum[tid] += v;
  }
  __syncthreads();

  float Dh = Dv[h];

  // ---- phase 1: G = C_l · B^T (global frags), decay+mask(+D/dt diag) -> M_lds bf16
  {
    f32x4 acc1[4][4];
    #pragma unroll
    for (int m = 0; m < 4; ++m)
      #pragma unroll
      for (int n = 0; n < 4; ++n) acc1[m][n] = (f32x4){0.f, 0.f, 0.f, 0.f};
    for (int kk = 0; kk < NSTATE; kk += 32) {
      bf16x8 af[4], bv[4];
      #pragma unroll
      for (int m = 0; m < 4; ++m)
        af[m] = *(const bf16x8*)(Cb + (row0 + lt * 64 + m * 16 + l16) * NSTATE + kk + lhi * 8);
      #pragma unroll
      for (int n = 0; n < 4; ++n)
        bv[n] = *(const bf16x8*)(Bb + (row0 + wave * 64 + n * 16 + l16) * NSTATE + kk + lhi * 8);
      #pragma unroll
      for (int m = 0; m < 4; ++m)
        #pragma unroll
        for (int n = 0; n < 4; ++n)
          acc1[m][n] = __builtin_amdgcn_mfma_f32_16x16x32_bf16(af[m], bv[n], acc1[m][n], 0, 0, 0);
    }
    float as_[4]; int sg_[4];
    #pragma unroll
    for (int n = 0; n < 4; ++n) { sg_[n] = wave * 64 + n * 16 + l16; as_[n] = acum[sg_[n]]; }
    #pragma unroll
    for (int m = 0; m < 4; ++m) {
      #pragma unroll
      for (int j = 0; j < 4; ++j) {
        int ll = m * 16 + lhi * 4 + j;
        int lg = lt * 64 + ll;
        float al = acum[lg];
        float dinv = Dh / fmaxf(sdt[lg], 1e-20f);
        #pragma unroll
        for (int n = 0; n < 4; ++n) {
          float v = 0.f;
          if (sg_[n] <= lg) {
            v = acc1[m][n][j] * __expf(al - as_[n]);
            if (sg_[n] == lg) v += dinv;
          }
          M_lds[ll * 264 + wave * 64 + n * 16 + l16] = f2bf(v);
        }
      }
    }
  }
  __syncthreads();

  const short* xbase = xsT + ((size_t)(b * 32 + h) * 128) * SEQ + s0;

  // ---- phase 2: Y_diag = M' @ xdt  (xdt^T frags direct from xsT global)
  f32x4 accY[4][2];
  #pragma unroll
  for (int m = 0; m < 4; ++m) { accY[m][0] = (f32x4){0,0,0,0}; accY[m][1] = (f32x4){0,0,0,0}; }
  int smax = (lt + 1) * 64;
  for (int st = 0; st < smax; st += 32) {
    float fe[8];
    #pragma unroll
    for (int e = 0; e < 8; ++e) fe[e] = sdt[st + lhi * 8 + e];
    bf16x8 bv2[2];
    #pragma unroll
    for (int n = 0; n < 2; ++n) {
      bf16x8 raw = *(const bf16x8*)(xbase + (size_t)(wave * 32 + n * 16 + l16) * SEQ + st + lhi * 8);
      bf16x8 sc;
      #pragma unroll
      for (int e = 0; e < 8; ++e) sc[e] = f2bf(bf2f(raw[e]) * fe[e]);
      bv2[n] = sc;
    }
    #pragma unroll
    for (int m = 0; m < 4; ++m) {
      bf16x8 a = *(const bf16x8*)(M_lds + (m * 16 + l16) * 264 + st + lhi * 8);
      accY[m][0] = __builtin_amdgcn_mfma_f32_16x16x32_bf16(a, bv2[0], accY[m][0], 0, 0, 0);
      accY[m][1] = __builtin_amdgcn_mfma_f32_16x16x32_bf16(a, bv2[1], accY[m][1], 0, 0, 0);
    }
  }

  // ---- phase 3: Y_off = C @ S_prev^T (S^T frags direct from cs f32 global)
  f32x4 accO[4][2];
  #pragma unroll
  for (int m = 0; m < 4; ++m) { accO[m][0] = (f32x4){0,0,0,0}; accO[m][1] = (f32x4){0,0,0,0}; }
  size_t pbase = (size_t)blk * 16384;
  for (int nt = 0; nt < NSTATE; nt += 32) {
    bf16x8 bv2[2];
    #pragma unroll
    for (int n = 0; n < 2; ++n) {
      int p = wave * 32 + n * 16 + l16;
      const float* src = cs + pbase + (size_t)p * NSTATE + nt + lhi * 8;
      f32x4 v0 = *(const f32x4*)src;
      f32x4 v1 = *(const f32x4*)(src + 4);
      bf16x8 sc;
      sc[0] = f2bf(v0.x); sc[1] = f2bf(v0.y); sc[2] = f2bf(v0.z); sc[3] = f2bf(v0.w);
      sc[4] = f2bf(v1.x); sc[5] = f2bf(v1.y); sc[6] = f2bf(v1.z); sc[7] = f2bf(v1.w);
      bv2[n] = sc;
    }
    #pragma unroll
    for (int m = 0; m < 4; ++m) {
      bf16x8 a = *(const bf16x8*)(Cb + (row0 + lt * 64 + m * 16 + l16) * NSTATE + nt + lhi * 8);
      accO[m][0] = __builtin_amdgcn_mfma_f32_16x16x32_bf16(a, bv2[0], accO[m][0], 0, 0, 0);
      accO[m][1] = __builtin_amdgcn_mfma_f32_16x16x32_bf16(a, bv2[1], accO[m][1], 0, 0, 0);
    }
  }

  // ---- epilogue: Y = accY + exp(acum[l])*accO; gate in place
  #pragma unroll
  for (int m = 0; m < 4; ++m) {
    #pragma unroll
    for (int j = 0; j < 4; ++j) {
      int ll = m * 16 + lhi * 4 + j;
      float e = __expf(acum[lt * 64 + ll]);
      size_t row = row0 + lt * 64 + ll;
      #pragma unroll
      for (int n = 0; n < 2; ++n) {
        int p = wave * 32 + n * 16 + l16;
        size_t adr = row * INTER_ + h * HDIM + p;
        float yv = accY[m][n][j] + e * accO[m][n][j];
        float g = bf2f(gateY[adr]);
        gateY[adr] = f2bf(yv * g / (1.f + expf(-g)));
      }
    }
  }
}

// ---------------- RMSNorm in-place on bf16 gated y ----------------
__global__ __launch_bounds__(256)
void gate_norm(short* __restrict__ ybf, const float* __restrict__ nw)
{
  int row = blockIdx.x;
  int tid = threadIdx.x;
  size_t base = (size_t)row * INTER_;
  float vals[16];
  float ss = 0.f;
  #pragma unroll
  for (int i = 0; i < 16; ++i) {
    int idx = tid + i * 256;
    float v = bf2f(ybf[base + idx]);
    vals[i] = v;
    ss += v * v;
  }
  #pragma unroll
  for (int off = 32; off > 0; off >>= 1) ss += __shfl_down(ss, off);
  __shared__ float ws4[4];
  if ((tid & 63) == 0) ws4[tid >> 6] = ss;
  __syncthreads();
  float tot = ws4[0] + ws4[1] + ws4[2] + ws4[3];
  float scale = rsqrtf(tot * (1.f / 4096.f) + 1e-5f);
  #pragma unroll
  for (int i = 0; i < 16; ++i) {
    int idx = tid + i * 256;
    ybf[base + idx] = f2bf(vals[i] * scale * nw[idx]);
  }
}

// ---------------- launch ----------------
extern "C" void kernel_launch(void* const* d_in, const int* in_sizes, int n_in,
                              void* d_out, int out_size, void* d_ws, size_t ws_size,
                              hipStream_t stream)
{
  const float* Xf   = (const float*)d_in[0];
  const float* W1f  = (const float*)d_in[1];
  const float* cw   = (const float*)d_in[2];
  const float* cb   = (const float*)d_in[3];
  const float* Alog = (const float*)d_in[4];
  const float* dtb  = (const float*)d_in[5];
  const float* Dv   = (const float*)d_in[6];
  const float* nw   = (const float*)d_in[7];
  const float* W2f  = (const float*)d_in[8];
  float* outp = (float*)d_out;
  char* ws = (char*)d_ws;

  // ---- workspace layout: ~232.3 MB (lifetime-aliased) ----
  size_t off = 0;
  short* Xb  = (short*)(ws + off); off += (size_t)NROWS * HID * 2;      // 33.55 MB
  short* W1b = (short*)(ws + off); off += (size_t)NPAD * HID * 2;       // 35.13 MB (zero-padded)
  short* xsT = (short*)ws;   // alias over Xb+W1b (dead after gemm1): 67.1 <= 68.7 MB
  short* W2b = (short*)(ws + off); off += (size_t)HID * INTER_ * 2;     // 16.78 MB
  short* gateY = (short*)(ws + off); off += (size_t)NROWS * INTER_ * 2; // 67.11 MB
  short* hbc  = (short*)(ws + off); off += (size_t)NROWS * CDIM * 2;    // 71.30 MB
  float* dtv  = (float*)(ws + off); off += (size_t)NROWS * NHEADS * 4;  // 1.05 MB
  float* dtT  = (float*)(ws + off); off += (size_t)NROWS * NHEADS * 4;  // 1.05 MB
  short* Bb   = (short*)(ws + off); off += (size_t)NROWS * NSTATE * 2;  // 2.10 MB
  short* Cb   = (short*)(ws + off); off += (size_t)NROWS * NSTATE * 2;  // 2.10 MB
  short* BbT  = (short*)(ws + off); off += (size_t)NROWS * NSTATE * 2;  // 2.10 MB
  float* dAs  = (float*)(ws + off); off += 4096;
  float* cs   = (float*)hbc;  // alias over hbc (dead after conv): 67.1 <= 71.3 MB

  cvt_bf16<<<(NROWS * HID / 4 + 255) / 256, 256, 0, stream>>>(
      Xf, Xb, NROWS * HID / 4, NROWS * HID / 4);
  cvt_bf16<<<(NPAD * HID / 4 + 255) / 256, 256, 0, stream>>>(
      W1f, W1b, NPAD * HID / 4, NPROJ_ * HID / 4);
  cvt_bf16<<<(HID * INTER_ / 4 + 255) / 256, 256, 0, stream>>>(
      W2f, W2b, HID * INTER_ / 4, HID * INTER_ / 4);

  gemm_bf16<1><<<dim3(NROWS / 128, NPAD / 128), 256, 0, stream>>>(
      Xb, W1b, NROWS, NPROJ_, HID, nullptr, gateY, hbc, dtv);

  dt_proc<<<(NROWS * NHEADS) / 256, 256, 0, stream>>>(dtv, dtb, dtT, NROWS * NHEADS);
  conv_t<<<dim3(NROWS / 64, 34), 256, 0, stream>>>(hbc, cw, cb, xsT, Bb, Cb, BbT);

  ssm_state<<<BATCH * NCH * NHEADS, 256, 0, stream>>>(xsT, BbT, dtT, Alog, cs, dAs);
  ssm_scan<<<(BATCH * NHEADS * 16384) / 256, 256, 0, stream>>>(cs, dAs);
  ssm_y<<<dim3(4, BATCH * NCH * NHEADS), 256, 0, stream>>>(xsT, Bb, Cb, dtT, Alog, Dv, cs, gateY);

  gate_norm<<<NROWS, 256, 0, stream>>>(gateY, nw);

  gemm_bf16<0><<<dim3(NROWS / 128, HID / 128), 256, 0, stream>>>(
      gateY, W2b, NROWS, HID, INTER_, outp, nullptr, nullptr, nullptr);
}